// Round 1
// baseline (189.726 us; speedup 1.0000x reference)
//
#include <hip/hip_runtime.h>
#include <hip/hip_bf16.h>
#include <cstddef>

#define NUM_VARS_ 784
#define NUM_PARAM_ 64
#define NET_DIM_ 64
#define FF_DIM_ 64
#define QTOT_ 2048

typedef short v8s __attribute__((ext_vector_type(8)));
typedef float v4f __attribute__((ext_vector_type(4)));

__device__ __forceinline__ short f2bf(float x) {
  union { float f; unsigned u; } c; c.f = x;
  unsigned r = c.u + 0x7FFFu + ((c.u >> 16) & 1u);
  return (short)(r >> 16);
}

__device__ __forceinline__ float fast_tanh(float x) {
  float cx = fminf(fmaxf(x, -9.0f), 9.0f);
  float t = __builtin_amdgcn_exp2f(cx * 2.8853900817779268f); // e^(2x)
  return 1.0f - 2.0f * __builtin_amdgcn_rcpf(t + 1.0f);
}

// ---- Prologue: feat[q][j] = j<32 ? cos(2pi*z[q]*c[j]) : sin(2pi*z[q]*c[j-32]),
// stored bf16 row-major (Q x 64) in workspace.
__global__ __launch_bounds__(256) void feat_kernel(
    const float* __restrict__ z, const float* __restrict__ coeff,
    short* __restrict__ featbf) {
  int i = blockIdx.x * 256 + threadIdx.x;
  if (i >= QTOT_ * FF_DIM_) return;
  int q = i >> 6, j = i & 63;
  float arg = (6.2831853071795865f * z[q]) * coeff[j & 31];
  float v = (j < 32) ? cosf(arg) : sinf(arg);
  featbf[i] = f2bf(v);
}

// ---- Fused main: per block = (q-chunk of 256, group g); 4 waves, each wave
// owns 64 q rows (4 m-frags of 16). GEMM1 (feat x W1^T) -> tanh -> LDS slice ->
// GEMM2 (h^T x W2^T) -> transposed store.
__global__ __launch_bounds__(256) void picnet_main(
    const float* __restrict__ W1, const float* __restrict__ W2,
    const short* __restrict__ featbf, float* __restrict__ out) {
  const int g = blockIdx.y;
  const int qc = blockIdx.x;
  const int tid = threadIdx.x;
  const int w = tid >> 6;
  const int lane = tid & 63;
  const int lo = lane & 15;
  const int hi = lane >> 4;

  // per-wave h^T slice: 16 q rows x 64 n, stride 72 (pad 8) -> writes <=2-way,
  // ds_read_b128 ~conflict-free. 4*16*72*2B = 9.2 KB.
  __shared__ __align__(16) short hl[4][16][72];

  // B-fragments for both GEMMs, held in VGPRs for the whole block.
  // B[k][n]: lane holds n = 16f+lo, k = k0*32 + hi*8 + j  (j=0..7 contiguous)
  v8s b1[4][2], b2[4][2];
  const float* W1g = W1 + (size_t)g * (NET_DIM_ * FF_DIM_);
  const float* W2g = W2 + (size_t)g * (NUM_PARAM_ * NET_DIM_);
#pragma unroll
  for (int f = 0; f < 4; ++f) {
#pragma unroll
    for (int k0 = 0; k0 < 2; ++k0) {
      const float* p1 = W1g + (16 * f + lo) * 64 + k0 * 32 + hi * 8;
      const float* p2 = W2g + (16 * f + lo) * 64 + k0 * 32 + hi * 8;
      float4 a = *(const float4*)p1;
      float4 b = *(const float4*)(p1 + 4);
      float4 c = *(const float4*)p2;
      float4 d = *(const float4*)(p2 + 4);
      v8s t1, t2;
      t1[0] = f2bf(a.x); t1[1] = f2bf(a.y); t1[2] = f2bf(a.z); t1[3] = f2bf(a.w);
      t1[4] = f2bf(b.x); t1[5] = f2bf(b.y); t1[6] = f2bf(b.z); t1[7] = f2bf(b.w);
      t2[0] = f2bf(c.x); t2[1] = f2bf(c.y); t2[2] = f2bf(c.z); t2[3] = f2bf(c.w);
      t2[4] = f2bf(d.x); t2[5] = f2bf(d.y); t2[6] = f2bf(d.z); t2[7] = f2bf(d.w);
      b1[f][k0] = t1; b2[f][k0] = t2;
    }
  }

  const int qbase = qc * 256 + w * 64;
#pragma unroll 1
  for (int mf = 0; mf < 4; ++mf) {
    const int q0 = qbase + mf * 16;

    // GEMM1 A-frag: A[q][k]: lane row q = q0+lo, k = k0*32 + hi*8 + j
    const short* fp = featbf + (size_t)(q0 + lo) * 64 + hi * 8;
    v8s a0 = *(const v8s*)fp;
    v8s a1 = *(const v8s*)(fp + 32);

    v4f acc[4] = {{0,0,0,0},{0,0,0,0},{0,0,0,0},{0,0,0,0}};
#pragma unroll
    for (int f = 0; f < 4; ++f) {
      acc[f] = __builtin_amdgcn_mfma_f32_16x16x32_bf16(a0, b1[f][0], acc[f], 0, 0, 0);
      acc[f] = __builtin_amdgcn_mfma_f32_16x16x32_bf16(a1, b1[f][1], acc[f], 0, 0, 0);
    }

    // D layout: col = lo (n = 16f+lo), row = hi*4+r (q_local). tanh -> bf16 -> LDS.
#pragma unroll
    for (int f = 0; f < 4; ++f)
#pragma unroll
      for (int r = 0; r < 4; ++r)
        hl[w][hi * 4 + r][16 * f + lo] = f2bf(fast_tanh(acc[f][r]));

    // GEMM2 A-frag from LDS: A[q][n]: row q = lo, n = k0*32 + hi*8 + j
    v8s h0 = *(const v8s*)(&hl[w][lo][hi * 8]);
    v8s h1 = *(const v8s*)(&hl[w][lo][32 + hi * 8]);

    v4f acc2[4] = {{0,0,0,0},{0,0,0,0},{0,0,0,0},{0,0,0,0}};
#pragma unroll
    for (int f = 0; f < 4; ++f) {
      acc2[f] = __builtin_amdgcn_mfma_f32_16x16x32_bf16(h0, b2[f][0], acc2[f], 0, 0, 0);
      acc2[f] = __builtin_amdgcn_mfma_f32_16x16x32_bf16(h1, b2[f][1], acc2[f], 0, 0, 0);
    }

    // out^T[q][p]: col p = 16f+lo, row q_local = hi*4+r.
    // param flat index: (g*2048 + q)*64 + p
    float* og = out + ((size_t)g * QTOT_ + q0) * 64;
#pragma unroll
    for (int f = 0; f < 4; ++f)
#pragma unroll
      for (int r = 0; r < 4; ++r)
        og[(hi * 4 + r) * 64 + 16 * f + lo] = acc2[f][r];
  }
}

extern "C" void kernel_launch(void* const* d_in, const int* in_sizes, int n_in,
                              void* d_out, int out_size, void* d_ws, size_t ws_size,
                              hipStream_t stream) {
  const float* z     = (const float*)d_in[0];
  const float* coeff = (const float*)d_in[1];
  const float* W1    = (const float*)d_in[2];
  const float* W2    = (const float*)d_in[3];
  float* out = (float*)d_out;
  short* featbf = (short*)d_ws;  // 2048*64*2 = 256 KB

  feat_kernel<<<dim3((QTOT_ * FF_DIM_ + 255) / 256), dim3(256), 0, stream>>>(
      z, coeff, featbf);
  picnet_main<<<dim3(QTOT_ / 256, NUM_VARS_), dim3(256), 0, stream>>>(
      W1, W2, featbf, out);
}

// Round 3
// 120.869 us; speedup vs baseline: 1.5697x; 1.5697x over previous
//
#include <hip/hip_runtime.h>
#include <cstddef>

#define NUM_VARS_ 784
#define NUM_PARAM_ 64
#define NET_DIM_ 64
#define FF_DIM_ 64
#define QTOT_ 2048

typedef short v8s __attribute__((ext_vector_type(8)));
typedef short v4s_ __attribute__((ext_vector_type(4)));
typedef float v4f __attribute__((ext_vector_type(4)));

__device__ __forceinline__ short f2bf(float x) {
  union { float f; unsigned u; } c; c.f = x;
  unsigned r = c.u + 0x7FFFu + ((c.u >> 16) & 1u);
  return (short)(r >> 16);
}

__device__ __forceinline__ float fast_tanh(float x) {
  float cx = fminf(fmaxf(x, -9.0f), 9.0f);
  float t = __builtin_amdgcn_exp2f(cx * 2.8853900817779268f); // e^(2x)
  return 1.0f - 2.0f * __builtin_amdgcn_rcpf(t + 1.0f);
}

// ---- Fourier features: feat[q][j] = j<32 ? cos : sin, bf16 row-major (Q x 64)
__global__ __launch_bounds__(256) void feat_kernel(
    const float* __restrict__ z, const float* __restrict__ coeff,
    short* __restrict__ featbf) {
  int i = blockIdx.x * 256 + threadIdx.x;
  if (i >= QTOT_ * FF_DIM_) return;
  int q = i >> 6, j = i & 63;
  float arg = (6.2831853071795865f * z[q]) * coeff[j & 31];
  float v = (j < 32) ? cosf(arg) : sinf(arg);
  featbf[i] = f2bf(v);
}

// ---- One-shot f32 -> bf16 weight conversion (4 floats / thread)
__global__ __launch_bounds__(256) void convw_kernel(
    const float* __restrict__ w, short* __restrict__ o, int n4) {
  int i = blockIdx.x * 256 + threadIdx.x;
  if (i >= n4) return;
  float4 v = ((const float4*)w)[i];
  v4s_ s;
  s[0] = f2bf(v.x); s[1] = f2bf(v.y); s[2] = f2bf(v.z); s[3] = f2bf(v.w);
  ((v4s_*)o)[i] = s;
}

// ---- Fused main: block = (q-chunk of 256, group g); 4 waves, each wave owns
// 64 q rows (4 m-frags of 16). GEMM1 (feat x W1^T) -> tanh -> LDS ->
// GEMM2 computed as W2 x h (A=W2 rows p) so D gives 4 consecutive p per lane
// -> float4 nontemporal store.
template <bool PRE>
__global__ __launch_bounds__(256) void picnet_main(
    const float* __restrict__ W1f, const float* __restrict__ W2f,
    const short* __restrict__ W1b, const short* __restrict__ W2b,
    const short* __restrict__ featbf, float* __restrict__ out) {
  const int g = blockIdx.y;
  const int qc = blockIdx.x;
  const int tid = threadIdx.x;
  const int w = tid >> 6;
  const int lane = tid & 63;
  const int lo = lane & 15;
  const int hi = lane >> 4;

  // per-wave h^T slice: 16 q rows x 64 n, stride 72 (pad) -> <=2-way on write,
  // ~conflict-free ds_read_b128. 4*16*72*2B = 9.2 KB.
  __shared__ __align__(16) short hl[4][16][72];

  // Weight fragments, held in VGPRs for the whole block.
  // b1[f]: B-frag of GEMM1 (n = 16f+lo, k = k0*32 + hi*8 + j)
  // b2[f]: A-frag of GEMM2 (p = 16f+lo, k(=n-dim) = k0*32 + hi*8 + j)
  v8s b1[4][2], b2[4][2];
  if (PRE) {
    const short* W1g = W1b + (size_t)g * 4096;
    const short* W2g = W2b + (size_t)g * 4096;
#pragma unroll
    for (int f = 0; f < 4; ++f)
#pragma unroll
      for (int k0 = 0; k0 < 2; ++k0) {
        b1[f][k0] = *(const v8s*)(W1g + (16 * f + lo) * 64 + k0 * 32 + hi * 8);
        b2[f][k0] = *(const v8s*)(W2g + (16 * f + lo) * 64 + k0 * 32 + hi * 8);
      }
  } else {
    const float* W1g = W1f + (size_t)g * 4096;
    const float* W2g = W2f + (size_t)g * 4096;
#pragma unroll
    for (int f = 0; f < 4; ++f)
#pragma unroll
      for (int k0 = 0; k0 < 2; ++k0) {
        const float* p1 = W1g + (16 * f + lo) * 64 + k0 * 32 + hi * 8;
        const float* p2 = W2g + (16 * f + lo) * 64 + k0 * 32 + hi * 8;
        float4 a = *(const float4*)p1, b = *(const float4*)(p1 + 4);
        float4 c = *(const float4*)p2, d = *(const float4*)(p2 + 4);
        v8s t1, t2;
        t1[0] = f2bf(a.x); t1[1] = f2bf(a.y); t1[2] = f2bf(a.z); t1[3] = f2bf(a.w);
        t1[4] = f2bf(b.x); t1[5] = f2bf(b.y); t1[6] = f2bf(b.z); t1[7] = f2bf(b.w);
        t2[0] = f2bf(c.x); t2[1] = f2bf(c.y); t2[2] = f2bf(c.z); t2[3] = f2bf(c.w);
        t2[4] = f2bf(d.x); t2[5] = f2bf(d.y); t2[6] = f2bf(d.z); t2[7] = f2bf(d.w);
        b1[f][k0] = t1; b2[f][k0] = t2;
      }
  }

  const int qbase = qc * 256 + w * 64;
  const short* fp0 = featbf + (size_t)(qbase + lo) * 64 + hi * 8;

  // software-pipelined feat A-frags
  v8s a0 = *(const v8s*)fp0;
  v8s a1 = *(const v8s*)(fp0 + 32);

#pragma unroll 1
  for (int mf = 0; mf < 4; ++mf) {
    const int q0 = qbase + mf * 16;

    v8s na0, na1;
    if (mf < 3) {
      const short* fp = fp0 + (size_t)(mf + 1) * 16 * 64;
      na0 = *(const v8s*)fp;
      na1 = *(const v8s*)(fp + 32);
    }

    // GEMM1: D[q_local][n], rows q = q0+lo
    v4f acc[4] = {{0,0,0,0},{0,0,0,0},{0,0,0,0},{0,0,0,0}};
#pragma unroll
    for (int f = 0; f < 4; ++f) {
      acc[f] = __builtin_amdgcn_mfma_f32_16x16x32_bf16(a0, b1[f][0], acc[f], 0, 0, 0);
      acc[f] = __builtin_amdgcn_mfma_f32_16x16x32_bf16(a1, b1[f][1], acc[f], 0, 0, 0);
    }

    // D layout: col = lo (n = 16f+lo), row = hi*4+r (q_local). tanh -> bf16 -> LDS.
#pragma unroll
    for (int f = 0; f < 4; ++f)
#pragma unroll
      for (int r = 0; r < 4; ++r)
        hl[w][hi * 4 + r][16 * f + lo] = f2bf(fast_tanh(acc[f][r]));

    // GEMM2 B-frag from LDS: B[k=n][q]: col q = lo, k = k0*32 + hi*8 + j
    v8s h0 = *(const v8s*)(&hl[w][lo][hi * 8]);
    v8s h1 = *(const v8s*)(&hl[w][lo][32 + hi * 8]);

    // GEMM2: D[p_local][q_local] = sum_n W2[p][n] h[n][q]
    v4f acc2[4] = {{0,0,0,0},{0,0,0,0},{0,0,0,0},{0,0,0,0}};
#pragma unroll
    for (int f = 0; f < 4; ++f) {
      acc2[f] = __builtin_amdgcn_mfma_f32_16x16x32_bf16(b2[f][0], h0, acc2[f], 0, 0, 0);
      acc2[f] = __builtin_amdgcn_mfma_f32_16x16x32_bf16(b2[f][1], h1, acc2[f], 0, 0, 0);
    }

    // D: col = lo = q_local, row = hi*4+r = p within 16-block f.
    // lane's 4 regs = consecutive p -> dwordx4 nontemporal store.
    // out[(g*2048+q)*64 + p]
    float* og = out + ((size_t)g * QTOT_ + q0 + lo) * 64 + hi * 4;
#pragma unroll
    for (int f = 0; f < 4; ++f) {
      __builtin_nontemporal_store(acc2[f], (v4f*)(og + 16 * f));
    }

    a0 = na0; a1 = na1;
  }
}

extern "C" void kernel_launch(void* const* d_in, const int* in_sizes, int n_in,
                              void* d_out, int out_size, void* d_ws, size_t ws_size,
                              hipStream_t stream) {
  const float* z     = (const float*)d_in[0];
  const float* coeff = (const float*)d_in[1];
  const float* W1    = (const float*)d_in[2];
  const float* W2    = (const float*)d_in[3];
  float* out = (float*)d_out;

  // workspace layout (shorts): [0,131072) feat; [131072, +3211264) W1bf; then W2bf
  short* featbf = (short*)d_ws;
  short* W1b = featbf + 131072;
  short* W2b = W1b + 3211264;
  const size_t needed = (size_t)(131072 + 2 * 3211264) * 2;

  feat_kernel<<<dim3((QTOT_ * FF_DIM_ + 255) / 256), dim3(256), 0, stream>>>(
      z, coeff, featbf);

  if (ws_size >= needed) {
    const int n4 = 3211264 / 4;  // floats per weight tensor / 4
    convw_kernel<<<dim3((n4 + 255) / 256), dim3(256), 0, stream>>>(W1, W1b, n4);
    convw_kernel<<<dim3((n4 + 255) / 256), dim3(256), 0, stream>>>(W2, W2b, n4);
    picnet_main<true><<<dim3(QTOT_ / 256, NUM_VARS_), dim3(256), 0, stream>>>(
        W1, W2, W1b, W2b, featbf, out);
  } else {
    picnet_main<false><<<dim3(QTOT_ / 256, NUM_VARS_), dim3(256), 0, stream>>>(
        W1, W2, W1b, W2b, featbf, out);
  }
}

// Round 4
// 103.395 us; speedup vs baseline: 1.8350x; 1.1690x over previous
//
#include <hip/hip_runtime.h>
#include <cstddef>

#define NUM_VARS_ 784
#define NUM_PARAM_ 64
#define NET_DIM_ 64
#define FF_DIM_ 64
#define QTOT_ 2048
#define QCHUNK_ 512
#define N4_ 802816  // floats per weight tensor / 4

typedef short v8s __attribute__((ext_vector_type(8)));
typedef short v4s_ __attribute__((ext_vector_type(4)));
typedef float v4f __attribute__((ext_vector_type(4)));

__device__ __forceinline__ short f2bf(float x) {
  union { float f; unsigned u; } c; c.f = x;
  unsigned r = c.u + 0x7FFFu + ((c.u >> 16) & 1u);
  return (short)(r >> 16);
}

__device__ __forceinline__ float fast_tanh(float x) {
  float cx = fminf(fmaxf(x, -9.0f), 9.0f);
  float t = __builtin_amdgcn_exp2f(cx * 2.8853900817779268f); // e^(2x)
  return 1.0f - 2.0f * __builtin_amdgcn_rcpf(t + 1.0f);
}

// ---- Merged prologue: f32->bf16 weight conversion for W1,W2 (4 floats/thread)
// followed by Fourier features feat[q][j] (1 elem/thread), one launch.
__global__ __launch_bounds__(256) void prologue_kernel(
    const float* __restrict__ z, const float* __restrict__ coeff,
    const float* __restrict__ W1, const float* __restrict__ W2,
    short* __restrict__ featbf, short* __restrict__ W1b,
    short* __restrict__ W2b) {
  int i = blockIdx.x * 256 + threadIdx.x;
  if (i < 2 * N4_) {
    const float* src = (i < N4_) ? W1 : W2;
    short* dst = (i < N4_) ? W1b : W2b;
    int j = (i < N4_) ? i : i - N4_;
    float4 v = ((const float4*)src)[j];
    v4s_ s;
    s[0] = f2bf(v.x); s[1] = f2bf(v.y); s[2] = f2bf(v.z); s[3] = f2bf(v.w);
    ((v4s_*)dst)[j] = s;
  } else {
    int t = i - 2 * N4_;
    if (t < QTOT_ * FF_DIM_) {
      int q = t >> 6, j = t & 63;
      float arg = (6.2831853071795865f * z[q]) * coeff[j & 31];
      float v = (j < 32) ? cosf(arg) : sinf(arg);
      featbf[t] = f2bf(v);
    }
  }
}

// ---- Fused main: block = (q-chunk of 512, group g); 4 waves, each wave owns
// 128 q rows (8 m-frags of 16). GEMM1 computed as W1 x feat^T (D=[n][q], 4
// consecutive n per lane -> ds_write_b64) -> tanh -> LDS -> GEMM2 as W2 x h
// (D=[p][q], 4 consecutive p per lane) -> dwordx4 store.
template <bool PRE>
__global__ __launch_bounds__(256) void picnet_main(
    const float* __restrict__ W1f, const float* __restrict__ W2f,
    const short* __restrict__ W1b, const short* __restrict__ W2b,
    const short* __restrict__ featbf, float* __restrict__ out) {
  const int g = blockIdx.y;
  const int qc = blockIdx.x;
  const int tid = threadIdx.x;
  const int w = tid >> 6;
  const int lane = tid & 63;
  const int lo = lane & 15;
  const int hi = lane >> 4;

  // per-wave h slice: hl[q_local][n], 16 x 64, stride 72 (pad).
  __shared__ __align__(16) short hl[4][16][72];

  // Weight fragments in VGPRs for the whole block.
  // b1[f]: GEMM1 A-frag (row n = 16f+lo, k = k0*32 + hi*8 + j)
  // b2[f]: GEMM2 A-frag (row p = 16f+lo, k(=n) = k0*32 + hi*8 + j)
  v8s b1[4][2], b2[4][2];
  if (PRE) {
    const short* W1g = W1b + (size_t)g * 4096;
    const short* W2g = W2b + (size_t)g * 4096;
#pragma unroll
    for (int f = 0; f < 4; ++f)
#pragma unroll
      for (int k0 = 0; k0 < 2; ++k0) {
        b1[f][k0] = *(const v8s*)(W1g + (16 * f + lo) * 64 + k0 * 32 + hi * 8);
        b2[f][k0] = *(const v8s*)(W2g + (16 * f + lo) * 64 + k0 * 32 + hi * 8);
      }
  } else {
    const float* W1g = W1f + (size_t)g * 4096;
    const float* W2g = W2f + (size_t)g * 4096;
#pragma unroll
    for (int f = 0; f < 4; ++f)
#pragma unroll
      for (int k0 = 0; k0 < 2; ++k0) {
        const float* p1 = W1g + (16 * f + lo) * 64 + k0 * 32 + hi * 8;
        const float* p2 = W2g + (16 * f + lo) * 64 + k0 * 32 + hi * 8;
        float4 a = *(const float4*)p1, b = *(const float4*)(p1 + 4);
        float4 c = *(const float4*)p2, d = *(const float4*)(p2 + 4);
        v8s t1, t2;
        t1[0] = f2bf(a.x); t1[1] = f2bf(a.y); t1[2] = f2bf(a.z); t1[3] = f2bf(a.w);
        t1[4] = f2bf(b.x); t1[5] = f2bf(b.y); t1[6] = f2bf(b.z); t1[7] = f2bf(b.w);
        t2[0] = f2bf(c.x); t2[1] = f2bf(c.y); t2[2] = f2bf(c.z); t2[3] = f2bf(c.w);
        t2[4] = f2bf(d.x); t2[5] = f2bf(d.y); t2[6] = f2bf(d.z); t2[7] = f2bf(d.w);
        b1[f][k0] = t1; b2[f][k0] = t2;
      }
  }

  const int qbase = qc * QCHUNK_ + w * (QCHUNK_ / 4);
  const short* fp0 = featbf + (size_t)(qbase + lo) * 64 + hi * 8;

  // software-pipelined feat B-frags (B[k][q]: col q = lo, k = hi*8+j)
  v8s a0 = *(const v8s*)fp0;
  v8s a1 = *(const v8s*)(fp0 + 32);

#pragma unroll 1
  for (int mf = 0; mf < QCHUNK_ / 4 / 16; ++mf) {
    const int q0 = qbase + mf * 16;

    v8s na0, na1;
    if (mf < QCHUNK_ / 4 / 16 - 1) {
      const short* fp = fp0 + (size_t)(mf + 1) * 16 * 64;
      na0 = *(const v8s*)fp;
      na1 = *(const v8s*)(fp + 32);
    }

    // GEMM1: D[n][q] = sum_k W1[n][k] feat[q][k]
    v4f acc[4] = {{0,0,0,0},{0,0,0,0},{0,0,0,0},{0,0,0,0}};
#pragma unroll
    for (int f = 0; f < 4; ++f) {
      acc[f] = __builtin_amdgcn_mfma_f32_16x16x32_bf16(b1[f][0], a0, acc[f], 0, 0, 0);
      acc[f] = __builtin_amdgcn_mfma_f32_16x16x32_bf16(b1[f][1], a1, acc[f], 0, 0, 0);
    }

    // D: col = lo = q_local, row = hi*4+r = n within 16-block f.
    // 4 consecutive n per lane -> packed ds_write_b64 into hl[q][n].
#pragma unroll
    for (int f = 0; f < 4; ++f) {
      v4s_ s;
      s[0] = f2bf(fast_tanh(acc[f][0]));
      s[1] = f2bf(fast_tanh(acc[f][1]));
      s[2] = f2bf(fast_tanh(acc[f][2]));
      s[3] = f2bf(fast_tanh(acc[f][3]));
      *(v4s_*)(&hl[w][lo][16 * f + hi * 4]) = s;
    }

    // GEMM2 B-frag from LDS: B[k=n][q]: col q = lo, k = k0*32 + hi*8 + j
    v8s h0 = *(const v8s*)(&hl[w][lo][hi * 8]);
    v8s h1 = *(const v8s*)(&hl[w][lo][32 + hi * 8]);

    // GEMM2: D[p][q] = sum_n W2[p][n] h[n][q]
    v4f acc2[4] = {{0,0,0,0},{0,0,0,0},{0,0,0,0},{0,0,0,0}};
#pragma unroll
    for (int f = 0; f < 4; ++f) {
      acc2[f] = __builtin_amdgcn_mfma_f32_16x16x32_bf16(b2[f][0], h0, acc2[f], 0, 0, 0);
      acc2[f] = __builtin_amdgcn_mfma_f32_16x16x32_bf16(b2[f][1], h1, acc2[f], 0, 0, 0);
    }

    // D: col = lo = q_local, row = hi*4+r = p within 16-block f.
    // out[(g*2048+q)*64 + p], 4 consecutive p -> dwordx4 (plain, L2-merged).
    float* og = out + ((size_t)g * QTOT_ + q0 + lo) * 64 + hi * 4;
#pragma unroll
    for (int f = 0; f < 4; ++f) {
      *(v4f*)(og + 16 * f) = acc2[f];
    }

    a0 = na0; a1 = na1;
  }
}

extern "C" void kernel_launch(void* const* d_in, const int* in_sizes, int n_in,
                              void* d_out, int out_size, void* d_ws, size_t ws_size,
                              hipStream_t stream) {
  const float* z     = (const float*)d_in[0];
  const float* coeff = (const float*)d_in[1];
  const float* W1    = (const float*)d_in[2];
  const float* W2    = (const float*)d_in[3];
  float* out = (float*)d_out;

  // workspace layout (shorts): [0,131072) feat; then W1bf; then W2bf
  short* featbf = (short*)d_ws;
  short* W1b = featbf + 131072;
  short* W2b = W1b + 4 * N4_;
  const size_t needed = (size_t)(131072 + 8 * N4_) * 2;

  if (ws_size >= needed) {
    const int total = 2 * N4_ + QTOT_ * FF_DIM_;
    prologue_kernel<<<dim3((total + 255) / 256), dim3(256), 0, stream>>>(
        z, coeff, W1, W2, featbf, W1b, W2b);
    picnet_main<true><<<dim3(QTOT_ / QCHUNK_, NUM_VARS_), dim3(256), 0, stream>>>(
        W1, W2, W1b, W2b, featbf, out);
  } else {
    // fallback: feat only, in-kernel weight conversion
    prologue_kernel<<<dim3((QTOT_ * FF_DIM_ + 255) / 256), dim3(256), 0, stream>>>(
        z, coeff, W1, W2, featbf, W1b, W2b);  // weights portion skipped below
    picnet_main<false><<<dim3(QTOT_ / QCHUNK_, NUM_VARS_), dim3(256), 0, stream>>>(
        W1, W2, W1b, W2b, featbf, out);
  }
}